// Round 3
// baseline (6352.330 us; speedup 1.0000x reference)
//
#include <hip/hip_runtime.h>

typedef unsigned short u16;
typedef unsigned int u32;
typedef unsigned long long u64;
typedef float f32x4 __attribute__((ext_vector_type(4)));
typedef __bf16 bf16x8 __attribute__((ext_vector_type(8)));
typedef u16 u16x8 __attribute__((ext_vector_type(8)));

#define T_STEPS 512
#define BATCH 64
#define HDIM 1024
#define GDIM 4096            // 4*H
#define HS_ELEMS (33554432u) // 512*64*1024
#define XP_STEP 262144       // u16 per t in blocked Xp: 256 blk * 4 gate * 256

__device__ __forceinline__ u16 f2bf(float f) {
  union { float f; u32 u; } v; v.f = f;
  u32 r = v.u + 0x7fffu + ((v.u >> 16) & 1u);
  return (u16)(r >> 16);
}
__device__ __forceinline__ float bf2f(u16 b) {
  union { u32 u; float f; } v; v.u = ((u32)b) << 16;
  return v.f;
}
__device__ __forceinline__ float sigm(float x) { return 1.f / (1.f + __expf(-x)); }
__device__ __forceinline__ float tanh_fast(float x) { return 1.f - 2.f / (__expf(2.f * x) + 1.f); }

// ---------------------------------------------------------------------------
// Kernel 1: transpose+convert W_x, W_h: [1024][4096] fp32 -> [4096][1024] bf16.
// ---------------------------------------------------------------------------
__global__ void transpose_w(const float* __restrict__ Wx, const float* __restrict__ Wh,
                            u16* __restrict__ WxT, u16* __restrict__ WhT) {
  __shared__ float tile[32][33];
  const float* src = blockIdx.z ? Wh : Wx;
  u16* dst = blockIdx.z ? WhT : WxT;
  const int n0 = blockIdx.x * 32, k0 = blockIdx.y * 32;
  const int tx = threadIdx.x, ty = threadIdx.y;
#pragma unroll
  for (int i = 0; i < 4; ++i)
    tile[ty + i * 8][tx] = src[(size_t)(k0 + ty + i * 8) * GDIM + n0 + tx];
  __syncthreads();
#pragma unroll
  for (int i = 0; i < 4; ++i)
    dst[(size_t)(n0 + ty + i * 8) * HDIM + k0 + tx] = f2bf(tile[tx][ty + i * 8]);
}

// ---------------------------------------------------------------------------
// Kernel 2: Xp = bf16(X @ W_x + b) written in BLOCKED layout:
//   Xp[t][blk=bg*64+cg][gate][b_el*16+hc]  (u16)
// so the recurrence block's per-step data is 2KB contiguous.
// GEMM core unchanged from R1 (128x128 tile, 4 waves, BK=32, reg-staged).
// ---------------------------------------------------------------------------
__global__ __launch_bounds__(256, 2) void gemm_xp(
    const float* __restrict__ X, const u16* __restrict__ WxT,
    const float* __restrict__ bias, u16* __restrict__ Xp) {
  __shared__ u16 As[128 * 40];
  __shared__ u16 Bs[128 * 40];
  const int tid = threadIdx.x;
  const int lane = tid & 63, w = tid >> 6;
  const int rl = lane & 15, gq = lane >> 4, g8 = gq * 8;
  const int swz = (blockIdx.x & 7) * 1024 + (blockIdx.x >> 3);
  const int m0 = (swz >> 5) * 128, n0 = (swz & 31) * 128;
  const int srow = tid >> 1, sseg = (tid & 1) * 16;
  const int rbase = (w >> 1) * 64, cbase = (w & 1) * 64;

  f32x4 acc[4][4] = {};
  for (int k0 = 0; k0 < 1024; k0 += 32) {
    const float4* ap = (const float4*)&X[(size_t)(m0 + srow) * 1024 + k0 + sseg];
    float4 v0 = ap[0], v1 = ap[1], v2 = ap[2], v3 = ap[3];
    u16x8 pa, pb;
    pa[0] = f2bf(v0.x); pa[1] = f2bf(v0.y); pa[2] = f2bf(v0.z); pa[3] = f2bf(v0.w);
    pa[4] = f2bf(v1.x); pa[5] = f2bf(v1.y); pa[6] = f2bf(v1.z); pa[7] = f2bf(v1.w);
    pb[0] = f2bf(v2.x); pb[1] = f2bf(v2.y); pb[2] = f2bf(v2.z); pb[3] = f2bf(v2.w);
    pb[4] = f2bf(v3.x); pb[5] = f2bf(v3.y); pb[6] = f2bf(v3.z); pb[7] = f2bf(v3.w);
    const u16x8* bp = (const u16x8*)&WxT[(size_t)(n0 + srow) * 1024 + k0 + sseg];
    u16x8 qa = bp[0], qb = bp[1];
    *(u16x8*)&As[srow * 40 + sseg] = pa;
    *(u16x8*)&As[srow * 40 + sseg + 8] = pb;
    *(u16x8*)&Bs[srow * 40 + sseg] = qa;
    *(u16x8*)&Bs[srow * 40 + sseg + 8] = qb;
    __syncthreads();
    bf16x8 av[4], bv[4];
#pragma unroll
    for (int i = 0; i < 4; ++i)
      av[i] = *(const bf16x8*)&As[(rbase + i * 16 + rl) * 40 + g8];
#pragma unroll
    for (int j = 0; j < 4; ++j)
      bv[j] = *(const bf16x8*)&Bs[(cbase + j * 16 + rl) * 40 + g8];
#pragma unroll
    for (int i = 0; i < 4; ++i)
#pragma unroll
      for (int j = 0; j < 4; ++j)
        acc[i][j] = __builtin_amdgcn_mfma_f32_16x16x32_bf16(av[i], bv[j], acc[i][j], 0, 0, 0);
    __syncthreads();
  }
#pragma unroll
  for (int j = 0; j < 4; ++j) {
    const int n = n0 + cbase + j * 16 + rl;
    const float bj = bias[n];
    const int gate = n >> 10, colg = n & 1023;
    const int cgi = colg >> 4, hcx = colg & 15;
#pragma unroll
    for (int i = 0; i < 4; ++i)
#pragma unroll
      for (int r = 0; r < 4; ++r) {
        const int m = m0 + rbase + i * 16 + gq * 4 + r;
        const int tt = m >> 6, b = m & 63;
        Xp[(size_t)tt * XP_STEP + (size_t)((b >> 4) * 64 + cgi) * 1024 +
           gate * 256 + (b & 15) * 16 + hcx] = f2bf(acc[i][j][r] + bj);
      }
  }
}

// ---------------------------------------------------------------------------
// Kernel 3: zero the tag buffer (2 slots x 64 x 1024 u32 = 512KB).
// Runs every launch (replay safety), after gemm_xp (h_tag aliases WxT space).
// ---------------------------------------------------------------------------
__global__ void zero_tags(u32* __restrict__ ht) {
  ht[(size_t)blockIdx.x * 256 + threadIdx.x] = 0;
}

// ---------------------------------------------------------------------------
// Kernel 4: recurrence via tagged-dataflow (NO grid barrier, NO fences).
// 256 blocks = 4 bg-groups x 64 col-groups; only same-bg blocks communicate.
// h element = u32 (lo16: bf16 value, hi16: tag = step+1), 2-slot ping-pong.
// Producer: relaxed agent store, fire-and-forget.
// Consumer: polls its 16x1024 slice (32 u64/thread) until tags >= t.
// Safety: producing h(t) requires consuming all h(t-1) => when any block
// writes slot s for tag T+2, every block has finished reading tag T from s.
// ---------------------------------------------------------------------------
__global__ __launch_bounds__(256, 1) void lstm_rec(
    const u16* __restrict__ Xp, const u16* __restrict__ WhT,
    u32* __restrict__ h_tag, float* __restrict__ out) {
  __shared__ u16 h_lds[16 * 1024]; // [16 rows][1024 k] bf16, XOR-swizzled
  __shared__ float gate_lds[4][16][20];
  const int tid = threadIdx.x;
  const int lane = tid & 63, w = tid >> 6;
  const int rl = lane & 15, gq = lane >> 4;
  const int cg = blockIdx.x & 63, bg = blockIdx.x >> 6;

  // W_h fragments -> VGPRs for all 512 steps (wave w = gate w, cols cg*16+rl)
  bf16x8 wf[32];
  {
    const size_t gcol = (size_t)(w * 1024 + cg * 16 + rl) * HDIM + gq * 8;
#pragma unroll
    for (int kk = 0; kk < 32; ++kk)
      wf[kk] = *(const bf16x8*)&WhT[gcol + kk * 32];
  }

  const int b_el = tid >> 4, hc = tid & 15;
  const int srow = tid >> 4, sseg = tid & 15;
  const int swz_w = ((srow & 7) << 4) ^ ((srow & 1) << 6);
  const int swz_r = ((rl & 7) << 4) ^ ((rl & 1) << 6);
  float creg = 0.f, hreg = 0.f;

  const u16* xp_p = Xp + (size_t)blockIdx.x * 1024 + tid;
  float xg0 = bf2f(xp_p[0]), xg1 = bf2f(xp_p[256]),
        xg2 = bf2f(xp_p[512]), xg3 = bf2f(xp_p[768]);

  for (int t = 0; t < T_STEPS; ++t) {
    // prefetch next step's Xp (independent of h; overlaps poll latency)
    u16 nx0 = 0, nx1 = 0, nx2 = 0, nx3 = 0;
    if (t + 1 < T_STEPS) {
      const u16* p = xp_p + XP_STEP;
      nx0 = p[0]; nx1 = p[256]; nx2 = p[512]; nx3 = p[768];
    }

    f32x4 acc0 = {0.f, 0.f, 0.f, 0.f}, acc1 = {0.f, 0.f, 0.f, 0.f};
    if (t > 0) {
      // poll + stage h(t): thread covers row srow, element-pairs u*16+sseg
      const u64* hrow =
          (const u64*)(h_tag + (size_t)(t & 1) * 65536 + (size_t)(bg * 16 + srow) * 1024) + sseg;
      char* ldsrow = (char*)h_lds + srow * 2048;
      u32 pend = 0u;
#pragma unroll
      for (int u = 0; u < 32; ++u) {
        u64 v = __hip_atomic_load(&hrow[u * 16], __ATOMIC_RELAXED, __HIP_MEMORY_SCOPE_AGENT);
        const u32 t0 = (u32)(v >> 16) & 0xffffu, t1 = (u32)(v >> 48);
        const u32 pack = ((u32)v & 0xffffu) | (((u32)(v >> 32) & 0xffffu) << 16);
        *(u32*)(ldsrow + (((u * 16 + sseg) * 4) ^ swz_w)) = pack;
        if (t0 < (u32)t || t1 < (u32)t) pend |= (1u << u);
      }
      while (pend) {
        u32 m = pend;
        do {
          const int u = __ffs(m) - 1;
          m &= m - 1;
          u64 v = __hip_atomic_load(&hrow[u * 16], __ATOMIC_RELAXED, __HIP_MEMORY_SCOPE_AGENT);
          const u32 t0 = (u32)(v >> 16) & 0xffffu, t1 = (u32)(v >> 48);
          if (t0 >= (u32)t && t1 >= (u32)t) {
            const u32 pack = ((u32)v & 0xffffu) | (((u32)(v >> 32) & 0xffffu) << 16);
            *(u32*)(ldsrow + (((u * 16 + sseg) * 4) ^ swz_w)) = pack;
            pend &= ~(1u << (u32)u);
          }
        } while (m);
      }
      __syncthreads();
      const char* hrd = (const char*)h_lds + rl * 2048;
#pragma unroll
      for (int kk = 0; kk < 32; kk += 2) {
        bf16x8 a0 = *(const bf16x8*)(hrd + ((kk * 64 + gq * 16) ^ swz_r));
        bf16x8 a1 = *(const bf16x8*)(hrd + (((kk + 1) * 64 + gq * 16) ^ swz_r));
        acc0 = __builtin_amdgcn_mfma_f32_16x16x32_bf16(a0, wf[kk], acc0, 0, 0, 0);
        acc1 = __builtin_amdgcn_mfma_f32_16x16x32_bf16(a1, wf[kk + 1], acc1, 0, 0, 0);
      }
      acc0 += acc1;
    } else {
      __syncthreads();
    }
    // gate exchange (C layout: row=gq*4+r, col=rl)
#pragma unroll
    for (int r = 0; r < 4; ++r)
      gate_lds[w][gq * 4 + r][rl] = acc0[r];
    __syncthreads();
    // elementwise: thread owns (b_el, hc)
    {
      const float gi = gate_lds[0][b_el][hc] + xg0;
      const float gf = gate_lds[1][b_el][hc] + xg1;
      const float gg = gate_lds[2][b_el][hc] + xg2;
      const float go = gate_lds[3][b_el][hc] + xg3;
      const float iv = sigm(gi);
      const float fv = sigm(gf);
      const float gv = tanh_fast(gg);
      const float ov = sigm(go);
      creg = fv * creg + iv * gv;
      hreg = ov * tanh_fast(creg);
      out[((size_t)t * BATCH + bg * 16 + b_el) * HDIM + cg * 16 + hc] = hreg;
      const u32 wv = (u32)f2bf(hreg) | ((u32)(t + 1) << 16);
      __hip_atomic_store(
          &h_tag[(size_t)((t + 1) & 1) * 65536 + (size_t)(bg * 16 + b_el) * 1024 + cg * 16 + hc],
          wv, __ATOMIC_RELAXED, __HIP_MEMORY_SCOPE_AGENT);
    }
    xg0 = bf2f(nx0); xg1 = bf2f(nx1); xg2 = bf2f(nx2); xg3 = bf2f(nx3);
    xp_p += XP_STEP;
  }
  // hT, cT
  out[(size_t)HS_ELEMS + (size_t)(bg * 16 + b_el) * HDIM + cg * 16 + hc] = hreg;
  out[(size_t)HS_ELEMS + 65536u + (size_t)(bg * 16 + b_el) * HDIM + cg * 16 + hc] = creg;
}

// ---------------------------------------------------------------------------
// Workspace layout (bytes):
//   [0,        8388608)   WxT [4096][1024] bf16 (gemm only);
//                         h_tag (512KB) ALIASES [0, 524288) - zeroed after gemm
//   [8388608,  16777216)  WhT [4096][1024] bf16
//   [16777216, +256MB)    Xp blocked [512][256][4][256] u16
// total 285,212,672 B (within the R1/R2-proven footprint)
// ---------------------------------------------------------------------------
extern "C" void kernel_launch(void* const* d_in, const int* in_sizes, int n_in,
                              void* d_out, int out_size, void* d_ws, size_t ws_size,
                              hipStream_t stream) {
  const float* x = (const float*)d_in[0];
  const float* Wx = (const float*)d_in[1];
  const float* Wh = (const float*)d_in[2];
  const float* bias = (const float*)d_in[3];
  float* out = (float*)d_out;
  char* ws = (char*)d_ws;

  u16* WxT = (u16*)(ws + 0);
  u32* h_tag = (u32*)(ws + 0); // aliases WxT; live only after zero_tags
  u16* WhT = (u16*)(ws + 8388608);
  u16* Xp = (u16*)(ws + 16777216);

  transpose_w<<<dim3(128, 32, 2), dim3(32, 8), 0, stream>>>(Wx, Wh, WxT, WhT);
  gemm_xp<<<dim3(8192), dim3(256), 0, stream>>>(x, WxT, bias, Xp);
  zero_tags<<<dim3(512), dim3(256), 0, stream>>>(h_tag);
  lstm_rec<<<dim3(256), dim3(256), 0, stream>>>(Xp, WhT, h_tag, out);
}

// Round 4
// 3802.317 us; speedup vs baseline: 1.6706x; 1.6706x over previous
//
#include <hip/hip_runtime.h>

typedef unsigned short u16;
typedef unsigned int u32;
typedef unsigned long long u64;
typedef float f32x4 __attribute__((ext_vector_type(4)));
typedef __bf16 bf16x8 __attribute__((ext_vector_type(8)));
typedef u16 u16x8 __attribute__((ext_vector_type(8)));

#define T_STEPS 512
#define BATCH 64
#define HDIM 1024
#define GDIM 4096            // 4*H
#define HS_ELEMS (33554432u) // 512*64*1024
#define XP_STEP 262144       // u16 per t in blocked Xp: 256 blk * 4 gate * 256

__device__ __forceinline__ u16 f2bf(float f) {
  union { float f; u32 u; } v; v.f = f;
  u32 r = v.u + 0x7fffu + ((v.u >> 16) & 1u);
  return (u16)(r >> 16);
}
__device__ __forceinline__ float bf2f(u16 b) {
  union { u32 u; float f; } v; v.u = ((u32)b) << 16;
  return v.f;
}
__device__ __forceinline__ float sigm(float x) { return 1.f / (1.f + __expf(-x)); }
__device__ __forceinline__ float tanh_fast(float x) { return 1.f - 2.f / (__expf(2.f * x) + 1.f); }

// ---------------------------------------------------------------------------
// Kernel 1: transpose+convert W_x, W_h: [1024][4096] fp32 -> [4096][1024] bf16.
// ---------------------------------------------------------------------------
__global__ void transpose_w(const float* __restrict__ Wx, const float* __restrict__ Wh,
                            u16* __restrict__ WxT, u16* __restrict__ WhT) {
  __shared__ float tile[32][33];
  const float* src = blockIdx.z ? Wh : Wx;
  u16* dst = blockIdx.z ? WhT : WxT;
  const int n0 = blockIdx.x * 32, k0 = blockIdx.y * 32;
  const int tx = threadIdx.x, ty = threadIdx.y;
#pragma unroll
  for (int i = 0; i < 4; ++i)
    tile[ty + i * 8][tx] = src[(size_t)(k0 + ty + i * 8) * GDIM + n0 + tx];
  __syncthreads();
#pragma unroll
  for (int i = 0; i < 4; ++i)
    dst[(size_t)(n0 + ty + i * 8) * HDIM + k0 + tx] = f2bf(tile[tx][ty + i * 8]);
}

// ---------------------------------------------------------------------------
// Kernel 2: Xp = bf16(X @ W_x + b), blocked layout Xp[t][blk][gate][b*16+hc].
// (unchanged from R3)
// ---------------------------------------------------------------------------
__global__ __launch_bounds__(256, 2) void gemm_xp(
    const float* __restrict__ X, const u16* __restrict__ WxT,
    const float* __restrict__ bias, u16* __restrict__ Xp) {
  __shared__ u16 As[128 * 40];
  __shared__ u16 Bs[128 * 40];
  const int tid = threadIdx.x;
  const int lane = tid & 63, w = tid >> 6;
  const int rl = lane & 15, gq = lane >> 4, g8 = gq * 8;
  const int swz = (blockIdx.x & 7) * 1024 + (blockIdx.x >> 3);
  const int m0 = (swz >> 5) * 128, n0 = (swz & 31) * 128;
  const int srow = tid >> 1, sseg = (tid & 1) * 16;
  const int rbase = (w >> 1) * 64, cbase = (w & 1) * 64;

  f32x4 acc[4][4] = {};
  for (int k0 = 0; k0 < 1024; k0 += 32) {
    const float4* ap = (const float4*)&X[(size_t)(m0 + srow) * 1024 + k0 + sseg];
    float4 v0 = ap[0], v1 = ap[1], v2 = ap[2], v3 = ap[3];
    u16x8 pa, pb;
    pa[0] = f2bf(v0.x); pa[1] = f2bf(v0.y); pa[2] = f2bf(v0.z); pa[3] = f2bf(v0.w);
    pa[4] = f2bf(v1.x); pa[5] = f2bf(v1.y); pa[6] = f2bf(v1.z); pa[7] = f2bf(v1.w);
    pb[0] = f2bf(v2.x); pb[1] = f2bf(v2.y); pb[2] = f2bf(v2.z); pb[3] = f2bf(v2.w);
    pb[4] = f2bf(v3.x); pb[5] = f2bf(v3.y); pb[6] = f2bf(v3.z); pb[7] = f2bf(v3.w);
    const u16x8* bp = (const u16x8*)&WxT[(size_t)(n0 + srow) * 1024 + k0 + sseg];
    u16x8 qa = bp[0], qb = bp[1];
    *(u16x8*)&As[srow * 40 + sseg] = pa;
    *(u16x8*)&As[srow * 40 + sseg + 8] = pb;
    *(u16x8*)&Bs[srow * 40 + sseg] = qa;
    *(u16x8*)&Bs[srow * 40 + sseg + 8] = qb;
    __syncthreads();
    bf16x8 av[4], bv[4];
#pragma unroll
    for (int i = 0; i < 4; ++i)
      av[i] = *(const bf16x8*)&As[(rbase + i * 16 + rl) * 40 + g8];
#pragma unroll
    for (int j = 0; j < 4; ++j)
      bv[j] = *(const bf16x8*)&Bs[(cbase + j * 16 + rl) * 40 + g8];
#pragma unroll
    for (int i = 0; i < 4; ++i)
#pragma unroll
      for (int j = 0; j < 4; ++j)
        acc[i][j] = __builtin_amdgcn_mfma_f32_16x16x32_bf16(av[i], bv[j], acc[i][j], 0, 0, 0);
    __syncthreads();
  }
#pragma unroll
  for (int j = 0; j < 4; ++j) {
    const int n = n0 + cbase + j * 16 + rl;
    const float bj = bias[n];
    const int gate = n >> 10, colg = n & 1023;
    const int cgi = colg >> 4, hcx = colg & 15;
#pragma unroll
    for (int i = 0; i < 4; ++i)
#pragma unroll
      for (int r = 0; r < 4; ++r) {
        const int m = m0 + rbase + i * 16 + gq * 4 + r;
        const int tt = m >> 6, b = m & 63;
        Xp[(size_t)tt * XP_STEP + (size_t)((b >> 4) * 64 + cgi) * 1024 +
           gate * 256 + (b & 15) * 16 + hcx] = f2bf(acc[i][j][r] + bj);
      }
  }
}

// ---------------------------------------------------------------------------
// Kernel 3: zero h_tag (2 x 64 x 1024 u32) + flags (256 u32), every launch.
// grid 513 x 256 covers 131328 u32 exactly.
// ---------------------------------------------------------------------------
__global__ void zero_tags(u32* __restrict__ ht) {
  ht[(size_t)blockIdx.x * 256 + threadIdx.x] = 0;
}

// ---------------------------------------------------------------------------
// Kernel 4: recurrence. Tagged-dataflow + cheap readiness flags.
// 256 blocks = 4 bg-groups x 64 col-groups; only same-bg blocks communicate.
// Producer per step: h stores (u32 = tag<<16 | bf16) -> vmcnt(0) -> sync ->
//   one flag store (flags[bg*64+cg] = t+1) -> out stores (fire & forget).
// Consumer: polls 64 flags (4B/lane, one load/round) -> BULK-loads its 16x1024
//   slice in two register batches of 16 u64/thread (loads fully in flight,
//   ~2 LLC RTs instead of a serialized chain) -> unpack+stage to swizzled LDS.
//   Per-word tags are a safety net vs flag/data fabric reordering (rare path).
// ---------------------------------------------------------------------------
__global__ __launch_bounds__(256, 1) void lstm_rec(
    const u16* __restrict__ Xp, const u16* __restrict__ WhT,
    u32* __restrict__ h_tag, u32* __restrict__ flags, float* __restrict__ out) {
  __shared__ u16 h_lds[16 * 1024]; // [16 rows][1024 k] bf16, XOR-swizzled
  __shared__ float gate_lds[4][16][20];
  const int tid = threadIdx.x;
  const int lane = tid & 63, w = tid >> 6;
  const int rl = lane & 15, gq = lane >> 4;
  const int cg = blockIdx.x & 63, bg = blockIdx.x >> 6;

  // W_h fragments -> VGPRs for all 512 steps (wave w = gate w, cols cg*16+rl)
  bf16x8 wf[32];
  {
    const size_t gcol = (size_t)(w * 1024 + cg * 16 + rl) * HDIM + gq * 8;
#pragma unroll
    for (int kk = 0; kk < 32; ++kk)
      wf[kk] = *(const bf16x8*)&WhT[gcol + kk * 32];
  }

  const int b_el = tid >> 4, hc = tid & 15;
  const int srow = tid >> 4, sseg = tid & 15;
  const int swz_w = ((srow & 7) << 4) ^ ((srow & 1) << 6);
  const int swz_r = ((rl & 7) << 4) ^ ((rl & 1) << 6);
  float creg = 0.f, hreg = 0.f;

  const u16* xp_p = Xp + (size_t)blockIdx.x * 1024 + tid;
  float xg0 = bf2f(xp_p[0]), xg1 = bf2f(xp_p[256]),
        xg2 = bf2f(xp_p[512]), xg3 = bf2f(xp_p[768]);

  const u32* myflag = flags + bg * 64 + lane; // 64 lanes cover the 64 producers

  for (int t = 0; t < T_STEPS; ++t) {
    // prefetch next step's Xp (independent of h; overlaps poll/stage latency)
    u16 nx0 = 0, nx1 = 0, nx2 = 0, nx3 = 0;
    if (t + 1 < T_STEPS) {
      const u16* p = xp_p + XP_STEP;
      nx0 = p[0]; nx1 = p[256]; nx2 = p[512]; nx3 = p[768];
    }

    f32x4 acc0 = {0.f, 0.f, 0.f, 0.f}, acc1 = {0.f, 0.f, 0.f, 0.f};
    if (t > 0) {
      // ---- 1) cheap readiness wait: one 4B load per lane per round ----
      for (;;) {
        u32 f = __hip_atomic_load(myflag, __ATOMIC_RELAXED, __HIP_MEMORY_SCOPE_AGENT);
        if (__all((int)(f >= (u32)t))) break;
      }
      // ---- 2) one-shot bulk load + stage (two batches of 16 u64) ----
      const u64* hrow =
          (const u64*)(h_tag + (size_t)(t & 1) * 65536 + (size_t)(bg * 16 + srow) * 1024) + sseg;
      char* ldsrow = (char*)h_lds + srow * 2048;
      u32 pend = 0u;
#pragma unroll
      for (int half = 0; half < 2; ++half) {
        u64 v[16];
#pragma unroll
        for (int u = 0; u < 16; ++u)
          v[u] = __hip_atomic_load(&hrow[(half * 16 + u) * 16], __ATOMIC_RELAXED,
                                   __HIP_MEMORY_SCOPE_AGENT);
#pragma unroll
        for (int u = 0; u < 16; ++u) {
          const int uu = half * 16 + u;
          const u32 t0 = (u32)(v[u] >> 16) & 0xffffu, t1 = (u32)(v[u] >> 48);
          const u32 pack = ((u32)v[u] & 0xffffu) | (((u32)(v[u] >> 32) & 0xffffu) << 16);
          *(u32*)(ldsrow + (((uu * 16 + sseg) * 4) ^ swz_w)) = pack;
          if (t0 < (u32)t || t1 < (u32)t) pend |= (1u << uu);
        }
      }
      // rare straggler path (flag raced ahead of data in the fabric)
      while (__builtin_expect(pend != 0u, 0)) {
        const int uu = __ffs(pend) - 1;
        u64 vv = __hip_atomic_load(&hrow[uu * 16], __ATOMIC_RELAXED, __HIP_MEMORY_SCOPE_AGENT);
        const u32 t0 = (u32)(vv >> 16) & 0xffffu, t1 = (u32)(vv >> 48);
        if (t0 >= (u32)t && t1 >= (u32)t) {
          const u32 pack = ((u32)vv & 0xffffu) | (((u32)(vv >> 32) & 0xffffu) << 16);
          *(u32*)(ldsrow + (((uu * 16 + sseg) * 4) ^ swz_w)) = pack;
          pend &= pend - 1u;
        }
      }
      __syncthreads();
      const char* hrd = (const char*)h_lds + rl * 2048;
#pragma unroll
      for (int kk = 0; kk < 32; kk += 2) {
        bf16x8 a0 = *(const bf16x8*)(hrd + ((kk * 64 + gq * 16) ^ swz_r));
        bf16x8 a1 = *(const bf16x8*)(hrd + (((kk + 1) * 64 + gq * 16) ^ swz_r));
        acc0 = __builtin_amdgcn_mfma_f32_16x16x32_bf16(a0, wf[kk], acc0, 0, 0, 0);
        acc1 = __builtin_amdgcn_mfma_f32_16x16x32_bf16(a1, wf[kk + 1], acc1, 0, 0, 0);
      }
      acc0 += acc1;
    } else {
      __syncthreads();
    }
    // gate exchange (C layout: row=gq*4+r, col=rl)
#pragma unroll
    for (int r = 0; r < 4; ++r)
      gate_lds[w][gq * 4 + r][rl] = acc0[r];
    __syncthreads();
    // elementwise: thread owns (b_el, hc)
    {
      const float gi = gate_lds[0][b_el][hc] + xg0;
      const float gf = gate_lds[1][b_el][hc] + xg1;
      const float gg = gate_lds[2][b_el][hc] + xg2;
      const float go = gate_lds[3][b_el][hc] + xg3;
      const float iv = sigm(gi);
      const float fv = sigm(gf);
      const float gv = tanh_fast(gg);
      const float ov = sigm(go);
      creg = fv * creg + iv * gv;
      hreg = ov * tanh_fast(creg);
      // h store FIRST (acked before the flag is raised)
      const u32 wv = (u32)f2bf(hreg) | ((u32)(t + 1) << 16);
      __hip_atomic_store(
          &h_tag[(size_t)((t + 1) & 1) * 65536 + (size_t)(bg * 16 + b_el) * 1024 + cg * 16 + hc],
          wv, __ATOMIC_RELAXED, __HIP_MEMORY_SCOPE_AGENT);
    }
    asm volatile("s_waitcnt vmcnt(0)" ::: "memory"); // this wave's h stores acked
    __syncthreads();                                 // all waves acked
    if (tid == 0)
      __hip_atomic_store(&flags[bg * 64 + cg], (u32)(t + 1), __ATOMIC_RELAXED,
                         __HIP_MEMORY_SCOPE_AGENT);
    // out store AFTER the flag: HBM writes off the release critical path
    out[((size_t)t * BATCH + bg * 16 + b_el) * HDIM + cg * 16 + hc] = hreg;
    xg0 = bf2f(nx0); xg1 = bf2f(nx1); xg2 = bf2f(nx2); xg3 = bf2f(nx3);
    xp_p += XP_STEP;
  }
  // hT, cT
  out[(size_t)HS_ELEMS + (size_t)(bg * 16 + b_el) * HDIM + cg * 16 + hc] = hreg;
  out[(size_t)HS_ELEMS + 65536u + (size_t)(bg * 16 + b_el) * HDIM + cg * 16 + hc] = creg;
}

// ---------------------------------------------------------------------------
// Workspace layout (bytes):
//   [0,        524288)    h_tag: 2 slots x 64 x 1024 u32 (aliases WxT region)
//   [524288,   525312)    flags: 256 u32 (also inside dead WxT region)
//   [0,        8388608)   WxT (gemm only; dead before zero_tags runs)
//   [8388608,  16777216)  WhT [4096][1024] bf16
//   [16777216, +256MB)    Xp blocked [512][256][4][256] u16
// ---------------------------------------------------------------------------
extern "C" void kernel_launch(void* const* d_in, const int* in_sizes, int n_in,
                              void* d_out, int out_size, void* d_ws, size_t ws_size,
                              hipStream_t stream) {
  const float* x = (const float*)d_in[0];
  const float* Wx = (const float*)d_in[1];
  const float* Wh = (const float*)d_in[2];
  const float* bias = (const float*)d_in[3];
  float* out = (float*)d_out;
  char* ws = (char*)d_ws;

  u16* WxT = (u16*)(ws + 0);
  u32* h_tag = (u32*)(ws + 0);      // aliases WxT; live only after zero_tags
  u32* flags = (u32*)(ws + 524288); // ditto
  u16* WhT = (u16*)(ws + 8388608);
  u16* Xp = (u16*)(ws + 16777216);

  transpose_w<<<dim3(128, 32, 2), dim3(32, 8), 0, stream>>>(Wx, Wh, WxT, WhT);
  gemm_xp<<<dim3(8192), dim3(256), 0, stream>>>(x, WxT, bias, Xp);
  zero_tags<<<dim3(513), dim3(256), 0, stream>>>(h_tag);
  lstm_rec<<<dim3(256), dim3(256), 0, stream>>>(Xp, WhT, h_tag, flags, out);
}

// Round 5
// 3273.182 us; speedup vs baseline: 1.9407x; 1.1617x over previous
//
#include <hip/hip_runtime.h>

typedef unsigned short u16;
typedef unsigned int u32;
typedef unsigned long long u64;
typedef float f32x4 __attribute__((ext_vector_type(4)));
typedef __bf16 bf16x8 __attribute__((ext_vector_type(8)));
typedef u16 u16x8 __attribute__((ext_vector_type(8)));

#define T_STEPS 512
#define BATCH 64
#define HDIM 1024
#define GDIM 4096            // 4*H
#define HS_ELEMS (33554432u) // 512*64*1024
#define XP_STEP 262144       // u16 per t in blocked Xp: 256 blk * 4 gate * 256

__device__ __forceinline__ u16 f2bf(float f) {
  union { float f; u32 u; } v; v.f = f;
  u32 r = v.u + 0x7fffu + ((v.u >> 16) & 1u);
  return (u16)(r >> 16);
}
__device__ __forceinline__ float bf2f(u16 b) {
  union { u32 u; float f; } v; v.u = ((u32)b) << 16;
  return v.f;
}
__device__ __forceinline__ float sigm(float x) { return 1.f / (1.f + __expf(-x)); }
__device__ __forceinline__ float tanh_fast(float x) { return 1.f - 2.f / (__expf(2.f * x) + 1.f); }

// ---------------------------------------------------------------------------
// Kernel 1: transpose+convert W_x, W_h: [1024][4096] fp32 -> [4096][1024] bf16.
// ---------------------------------------------------------------------------
__global__ void transpose_w(const float* __restrict__ Wx, const float* __restrict__ Wh,
                            u16* __restrict__ WxT, u16* __restrict__ WhT) {
  __shared__ float tile[32][33];
  const float* src = blockIdx.z ? Wh : Wx;
  u16* dst = blockIdx.z ? WhT : WxT;
  const int n0 = blockIdx.x * 32, k0 = blockIdx.y * 32;
  const int tx = threadIdx.x, ty = threadIdx.y;
#pragma unroll
  for (int i = 0; i < 4; ++i)
    tile[ty + i * 8][tx] = src[(size_t)(k0 + ty + i * 8) * GDIM + n0 + tx];
  __syncthreads();
#pragma unroll
  for (int i = 0; i < 4; ++i)
    dst[(size_t)(n0 + ty + i * 8) * HDIM + k0 + tx] = f2bf(tile[tx][ty + i * 8]);
}

// ---------------------------------------------------------------------------
// Kernel 2: Xp = bf16(X @ W_x + b), blocked layout Xp[t][blk][gate][b*16+hc].
// (unchanged)
// ---------------------------------------------------------------------------
__global__ __launch_bounds__(256, 2) void gemm_xp(
    const float* __restrict__ X, const u16* __restrict__ WxT,
    const float* __restrict__ bias, u16* __restrict__ Xp) {
  __shared__ u16 As[128 * 40];
  __shared__ u16 Bs[128 * 40];
  const int tid = threadIdx.x;
  const int lane = tid & 63, w = tid >> 6;
  const int rl = lane & 15, gq = lane >> 4, g8 = gq * 8;
  const int swz = (blockIdx.x & 7) * 1024 + (blockIdx.x >> 3);
  const int m0 = (swz >> 5) * 128, n0 = (swz & 31) * 128;
  const int srow = tid >> 1, sseg = (tid & 1) * 16;
  const int rbase = (w >> 1) * 64, cbase = (w & 1) * 64;

  f32x4 acc[4][4] = {};
  for (int k0 = 0; k0 < 1024; k0 += 32) {
    const float4* ap = (const float4*)&X[(size_t)(m0 + srow) * 1024 + k0 + sseg];
    float4 v0 = ap[0], v1 = ap[1], v2 = ap[2], v3 = ap[3];
    u16x8 pa, pb;
    pa[0] = f2bf(v0.x); pa[1] = f2bf(v0.y); pa[2] = f2bf(v0.z); pa[3] = f2bf(v0.w);
    pa[4] = f2bf(v1.x); pa[5] = f2bf(v1.y); pa[6] = f2bf(v1.z); pa[7] = f2bf(v1.w);
    pb[0] = f2bf(v2.x); pb[1] = f2bf(v2.y); pb[2] = f2bf(v2.z); pb[3] = f2bf(v2.w);
    pb[4] = f2bf(v3.x); pb[5] = f2bf(v3.y); pb[6] = f2bf(v3.z); pb[7] = f2bf(v3.w);
    const u16x8* bp = (const u16x8*)&WxT[(size_t)(n0 + srow) * 1024 + k0 + sseg];
    u16x8 qa = bp[0], qb = bp[1];
    *(u16x8*)&As[srow * 40 + sseg] = pa;
    *(u16x8*)&As[srow * 40 + sseg + 8] = pb;
    *(u16x8*)&Bs[srow * 40 + sseg] = qa;
    *(u16x8*)&Bs[srow * 40 + sseg + 8] = qb;
    __syncthreads();
    bf16x8 av[4], bv[4];
#pragma unroll
    for (int i = 0; i < 4; ++i)
      av[i] = *(const bf16x8*)&As[(rbase + i * 16 + rl) * 40 + g8];
#pragma unroll
    for (int j = 0; j < 4; ++j)
      bv[j] = *(const bf16x8*)&Bs[(cbase + j * 16 + rl) * 40 + g8];
#pragma unroll
    for (int i = 0; i < 4; ++i)
#pragma unroll
      for (int j = 0; j < 4; ++j)
        acc[i][j] = __builtin_amdgcn_mfma_f32_16x16x32_bf16(av[i], bv[j], acc[i][j], 0, 0, 0);
    __syncthreads();
  }
#pragma unroll
  for (int j = 0; j < 4; ++j) {
    const int n = n0 + cbase + j * 16 + rl;
    const float bj = bias[n];
    const int gate = n >> 10, colg = n & 1023;
    const int cgi = colg >> 4, hcx = colg & 15;
#pragma unroll
    for (int i = 0; i < 4; ++i)
#pragma unroll
      for (int r = 0; r < 4; ++r) {
        const int m = m0 + rbase + i * 16 + gq * 4 + r;
        const int tt = m >> 6, b = m & 63;
        Xp[(size_t)tt * XP_STEP + (size_t)((b >> 4) * 64 + cgi) * 1024 +
           gate * 256 + (b & 15) * 16 + hcx] = f2bf(acc[i][j][r] + bj);
      }
  }
}

// ---------------------------------------------------------------------------
// Kernel 3: zero h_tag (2 slots x 64 x 1024 u32 = 512KB), every launch
// (replay safety; h_tag aliases the dead WxT region).
// ---------------------------------------------------------------------------
__global__ void zero_tags(u32* __restrict__ ht) {
  ht[(size_t)blockIdx.x * 256 + threadIdx.x] = 0;
}

// ---------------------------------------------------------------------------
// Kernel 4: recurrence. FLAGLESS tagged dataflow.
// 256 blocks = 4 bg-groups x 64 col-groups; only same-bg blocks communicate.
// h element = u32 (lo16: bf16 value, hi16: tag = step+1), 2-slot ping-pong.
// Producer: relaxed agent stores, fire-and-forget (no vmcnt, no flag, no
//   release barrier) — the tag IS the readiness signal.
// Consumer: batched predicated poll rounds over its 32 tagged u64 words:
//   each round re-issues ALL pending loads in one unrolled batch (~1 RT),
//   drains fresh words to swizzled LDS as they land.
// Slot safety (induction): producing h(t+1) requires consuming h(t); slot s
//   can only receive tag t+2 after every block produced t+1, i.e. after every
//   block consumed t from s.
// ---------------------------------------------------------------------------
__global__ __launch_bounds__(256, 1) void lstm_rec(
    const u16* __restrict__ Xp, const u16* __restrict__ WhT,
    u32* __restrict__ h_tag, float* __restrict__ out) {
  __shared__ u16 h_lds[16 * 1024]; // [16 rows][1024 k] bf16, XOR-swizzled
  __shared__ float gate_lds[4][16][20];
  const int tid = threadIdx.x;
  const int lane = tid & 63, w = tid >> 6;
  const int rl = lane & 15, gq = lane >> 4;
  const int cg = blockIdx.x & 63, bg = blockIdx.x >> 6;

  // W_h fragment pointers (wave w = gate w, cols cg*16+rl). The compiler
  // re-loads these from L2 each step (loop-invariant, issues early) — cheaper
  // than pinning 128 VGPRs (R4 evidence: VGPR_Count=132).
  bf16x8 wf[32];
  {
    const size_t gcol = (size_t)(w * 1024 + cg * 16 + rl) * HDIM + gq * 8;
#pragma unroll
    for (int kk = 0; kk < 32; ++kk)
      wf[kk] = *(const bf16x8*)&WhT[gcol + kk * 32];
  }

  const int b_el = tid >> 4, hc = tid & 15;
  const int srow = tid >> 4, sseg = tid & 15;
  const int swz_w = ((srow & 7) << 4) ^ ((srow & 1) << 6);
  const int swz_r = ((rl & 7) << 4) ^ ((rl & 1) << 6);
  float creg = 0.f, hreg = 0.f;

  const u16* xp_p = Xp + (size_t)blockIdx.x * 1024 + tid;
  float xg0 = bf2f(xp_p[0]), xg1 = bf2f(xp_p[256]),
        xg2 = bf2f(xp_p[512]), xg3 = bf2f(xp_p[768]);

  for (int t = 0; t < T_STEPS; ++t) {
    // prefetch next step's Xp (independent of h; overlaps poll latency)
    u16 nx0 = 0, nx1 = 0, nx2 = 0, nx3 = 0;
    if (t + 1 < T_STEPS) {
      const u16* p = xp_p + XP_STEP;
      nx0 = p[0]; nx1 = p[256]; nx2 = p[512]; nx3 = p[768];
    }

    f32x4 acc0 = {0.f, 0.f, 0.f, 0.f}, acc1 = {0.f, 0.f, 0.f, 0.f};
    if (t > 0) {
      // batched tag-poll + stage: thread covers row srow, 32 u64 (pairs)
      const u64* hrow =
          (const u64*)(h_tag + (size_t)(t & 1) * 65536 + (size_t)(bg * 16 + srow) * 1024) + sseg;
      char* ldsrow = (char*)h_lds + srow * 2048;
      u64 v[32];
      u32 pend = 0xffffffffu;
      while (pend) {
#pragma unroll
        for (int u = 0; u < 32; ++u)
          if (pend & (1u << u))
            v[u] = __hip_atomic_load(&hrow[u * 16], __ATOMIC_RELAXED, __HIP_MEMORY_SCOPE_AGENT);
        u32 got = 0u;
#pragma unroll
        for (int u = 0; u < 32; ++u)
          if (pend & (1u << u)) {
            const u32 t0 = (u32)(v[u] >> 16) & 0xffffu, t1 = (u32)(v[u] >> 48);
            if (t0 >= (u32)t && t1 >= (u32)t) {
              const u32 pack = ((u32)v[u] & 0xffffu) | (((u32)(v[u] >> 32) & 0xffffu) << 16);
              *(u32*)(ldsrow + (((u * 16 + sseg) * 4) ^ swz_w)) = pack;
              got |= (1u << u);
            }
          }
        pend &= ~got;
      }
      __syncthreads();
      const char* hrd = (const char*)h_lds + rl * 2048;
#pragma unroll
      for (int kk = 0; kk < 32; kk += 2) {
        bf16x8 a0 = *(const bf16x8*)(hrd + ((kk * 64 + gq * 16) ^ swz_r));
        bf16x8 a1 = *(const bf16x8*)(hrd + (((kk + 1) * 64 + gq * 16) ^ swz_r));
        acc0 = __builtin_amdgcn_mfma_f32_16x16x32_bf16(a0, wf[kk], acc0, 0, 0, 0);
        acc1 = __builtin_amdgcn_mfma_f32_16x16x32_bf16(a1, wf[kk + 1], acc1, 0, 0, 0);
      }
      acc0 += acc1;
    } else {
      __syncthreads();
    }
    // gate exchange (C layout: row=gq*4+r, col=rl)
#pragma unroll
    for (int r = 0; r < 4; ++r)
      gate_lds[w][gq * 4 + r][rl] = acc0[r];
    __syncthreads();
    // elementwise: thread owns (b_el, hc)
    {
      const float gi = gate_lds[0][b_el][hc] + xg0;
      const float gf = gate_lds[1][b_el][hc] + xg1;
      const float gg = gate_lds[2][b_el][hc] + xg2;
      const float go = gate_lds[3][b_el][hc] + xg3;
      const float iv = sigm(gi);
      const float fv = sigm(gf);
      const float gv = tanh_fast(gg);
      const float ov = sigm(go);
      creg = fv * creg + iv * gv;
      hreg = ov * tanh_fast(creg);
      // tagged h store FIRST (critical path), fire-and-forget
      const u32 wv = (u32)f2bf(hreg) | ((u32)(t + 1) << 16);
      __hip_atomic_store(
          &h_tag[(size_t)((t + 1) & 1) * 65536 + (size_t)(bg * 16 + b_el) * 1024 + cg * 16 + hc],
          wv, __ATOMIC_RELAXED, __HIP_MEMORY_SCOPE_AGENT);
      // out store after (off the critical path)
      out[((size_t)t * BATCH + bg * 16 + b_el) * HDIM + cg * 16 + hc] = hreg;
    }
    xg0 = bf2f(nx0); xg1 = bf2f(nx1); xg2 = bf2f(nx2); xg3 = bf2f(nx3);
    xp_p += XP_STEP;
  }
  // hT, cT
  out[(size_t)HS_ELEMS + (size_t)(bg * 16 + b_el) * HDIM + cg * 16 + hc] = hreg;
  out[(size_t)HS_ELEMS + 65536u + (size_t)(bg * 16 + b_el) * HDIM + cg * 16 + hc] = creg;
}

// ---------------------------------------------------------------------------
// Workspace layout (bytes):
//   [0,        524288)    h_tag: 2 slots x 64 x 1024 u32 (aliases WxT region)
//   [0,        8388608)   WxT (gemm only; dead before zero_tags runs)
//   [8388608,  16777216)  WhT [4096][1024] bf16
//   [16777216, +256MB)    Xp blocked [512][256][4][256] u16
// ---------------------------------------------------------------------------
extern "C" void kernel_launch(void* const* d_in, const int* in_sizes, int n_in,
                              void* d_out, int out_size, void* d_ws, size_t ws_size,
                              hipStream_t stream) {
  const float* x = (const float*)d_in[0];
  const float* Wx = (const float*)d_in[1];
  const float* Wh = (const float*)d_in[2];
  const float* bias = (const float*)d_in[3];
  float* out = (float*)d_out;
  char* ws = (char*)d_ws;

  u16* WxT = (u16*)(ws + 0);
  u32* h_tag = (u32*)(ws + 0); // aliases WxT; live only after zero_tags
  u16* WhT = (u16*)(ws + 8388608);
  u16* Xp = (u16*)(ws + 16777216);

  transpose_w<<<dim3(128, 32, 2), dim3(32, 8), 0, stream>>>(Wx, Wh, WxT, WhT);
  gemm_xp<<<dim3(8192), dim3(256), 0, stream>>>(x, WxT, bias, Xp);
  zero_tags<<<dim3(512), dim3(256), 0, stream>>>(h_tag);
  lstm_rec<<<dim3(256), dim3(256), 0, stream>>>(Xp, WhT, h_tag, out);
}